// Round 1
// baseline (266.867 us; speedup 1.0000x reference)
//
#include <hip/hip_runtime.h>
#include <hip/hip_bf16.h>

#define B_ 2
#define S_ 2048
#define D_ 1024
#define H_ 16
#define DH 64
#define QB 64
#define KB 32
#define NQB (S_/QB)     // 32
#define SCALE 0.125f    // 1/sqrt(64)

typedef _Float16 f16x8 __attribute__((ext_vector_type(8)));
typedef float f32x4 __attribute__((ext_vector_type(4)));

// A/B fragment layout for v_mfma_f32_16x16x32_f16 (gfx950):
//   A[m][k]: m = lane&15, k = (lane>>4)*8 + j   (8 contiguous k per lane -> ds_read_b128)
//   B[k][n]: n = lane&15, k = (lane>>4)*8 + j
//   D[row][col]: col = lane&15, row = (lane>>4)*4 + reg   [measured m89]

__global__ __launch_bounds__(256) void mha_fwd(
    const float* __restrict__ qg, const float* __restrict__ kg,
    const float* __restrict__ vg, float* __restrict__ out)
{
  // K tile: [32 keys][64 dh] halfs, XOR-swizzled (rows are 128B)
  __shared__ __align__(16) _Float16 lds_k[KB * DH];
  // V^T tile: [64 dh][40] halfs (stride 40 keeps rows 16B-aligned, banks spread)
  __shared__ __align__(16) _Float16 lds_v[DH * 40];
  // P buffer: per-wave [16 rows][40] halfs
  __shared__ __align__(16) _Float16 lds_p[4 * 16 * 40];

  // XCD-aware swizzle: grid=1024, 8 XCDs, bh-major chunks (work-balanced in qb)
  int bx = blockIdx.x;
  int L  = (bx & 7) * 128 + (bx >> 3);
  int qb = L & 31;
  int bh = L >> 5;
  int h  = bh & 15;
  int b  = bh >> 4;

  int tid  = threadIdx.x;
  int wid  = tid >> 6;
  int lane = tid & 63;
  int n    = lane & 15;   // col within 16-tile
  int g    = lane >> 4;   // k-group

  int qrow_base = qb * QB + wid * 16;   // this wave's 16 q-rows

  const float* qbase = qg + (size_t)b * S_ * D_ + h * DH;
  const float* kbase = kg + (size_t)b * S_ * D_ + h * DH;
  const float* vbase = vg + (size_t)b * S_ * D_ + h * DH;

  // ---- Q fragments (held in registers for the whole block) ----
  f16x8 aq[2];
  {
    const float* qp = qbase + (size_t)(qrow_base + n) * D_ + g * 8;
#pragma unroll
    for (int c = 0; c < 2; ++c) {
      float4 x0 = *(const float4*)(qp + c * 32);
      float4 x1 = *(const float4*)(qp + c * 32 + 4);
      f16x8 a;
      a[0] = (_Float16)(x0.x * SCALE); a[1] = (_Float16)(x0.y * SCALE);
      a[2] = (_Float16)(x0.z * SCALE); a[3] = (_Float16)(x0.w * SCALE);
      a[4] = (_Float16)(x1.x * SCALE); a[5] = (_Float16)(x1.y * SCALE);
      a[6] = (_Float16)(x1.z * SCALE); a[7] = (_Float16)(x1.w * SCALE);
      aq[c] = a;
    }
  }

  f32x4 o_acc[4] = {};              // 4 dh n-tiles x 4 rows
  float m_r[4], l_r[4];
#pragma unroll
  for (int r = 0; r < 4; ++r) { m_r[r] = -1e30f; l_r[r] = 0.f; }

  const int nkt = qb * 2 + 2;       // causal: keys up to qb*64+63
  for (int kt = 0; kt < nkt; ++kt) {
    const int kb = kt * KB;

    // ---- stage K tile (coalesced fp32 read, fp16 swizzled LDS write) ----
    {
      int key = tid >> 3, cg = tid & 7;
      const float* kp = kbase + (size_t)(kb + key) * D_ + cg * 8;
      float4 x0 = *(const float4*)kp;
      float4 x1 = *(const float4*)(kp + 4);
      f16x8 hk;
      hk[0] = (_Float16)x0.x; hk[1] = (_Float16)x0.y;
      hk[2] = (_Float16)x0.z; hk[3] = (_Float16)x0.w;
      hk[4] = (_Float16)x1.x; hk[5] = (_Float16)x1.y;
      hk[6] = (_Float16)x1.z; hk[7] = (_Float16)x1.w;
      int off = (key * 128 + cg * 16) ^ ((key & 7) << 4);
      *(f16x8*)((char*)lds_k + off) = hk;
    }
    // ---- stage V^T tile (interleaved d per thread -> conflict-free writes) ----
    {
      int key = tid >> 3, dc = tid & 7;
      const float* vp = vbase + (size_t)(kb + key) * D_ + dc;
#pragma unroll
      for (int i = 0; i < 8; ++i) {
        float x = vp[i * 8];
        lds_v[(dc + i * 8) * 40 + key] = (_Float16)x;
      }
    }
    __syncthreads();

    bool active = (kb <= qrow_base + 15);
    if (active) {
      // ---- QK^T: 2 key n-tiles x 2 k-chunks ----
      f32x4 sc[2] = {};
#pragma unroll
      for (int t = 0; t < 2; ++t) {
        int keyl = t * 16 + n;
#pragma unroll
        for (int c = 0; c < 2; ++c) {
          int off = (keyl * 128 + (c * 4 + g) * 16) ^ ((keyl & 7) << 4);
          f16x8 bk = *(f16x8*)((char*)lds_k + off);
          sc[t] = __builtin_amdgcn_mfma_f32_16x16x32_f16(aq[c], bk, sc[t], 0, 0, 0);
        }
      }
      // ---- causal mask (diagonal tiles only) ----
      if (kb + KB - 1 > qrow_base) {
#pragma unroll
        for (int t = 0; t < 2; ++t)
#pragma unroll
          for (int r = 0; r < 4; ++r) {
            int key = kb + t * 16 + n;
            int row = qrow_base + g * 4 + r;
            if (key > row) sc[t][r] = -1e30f;
          }
      }
      // ---- online softmax (rows live in 16-lane groups) ----
      float alpha[4];
#pragma unroll
      for (int r = 0; r < 4; ++r) {
        float mx = fmaxf(sc[0][r], sc[1][r]);
#pragma unroll
        for (int w = 1; w < 16; w <<= 1) mx = fmaxf(mx, __shfl_xor(mx, w, 64));
        float mnew = fmaxf(m_r[r], mx);
        float a  = __expf(m_r[r] - mnew);
        float p0 = __expf(sc[0][r] - mnew);
        float p1 = __expf(sc[1][r] - mnew);
        sc[0][r] = p0; sc[1][r] = p1;
        float s = p0 + p1;
#pragma unroll
        for (int w = 1; w < 16; w <<= 1) s += __shfl_xor(s, w, 64);
        l_r[r] = l_r[r] * a + s;
        m_r[r] = mnew;
        alpha[r] = a;
      }
#pragma unroll
      for (int nt = 0; nt < 4; ++nt)
#pragma unroll
        for (int r = 0; r < 4; ++r) o_acc[nt][r] *= alpha[r];

      // ---- P -> LDS (layout change score->A-fragment), per-wave buffer ----
      _Float16* pw = lds_p + wid * 16 * 40;
#pragma unroll
      for (int t = 0; t < 2; ++t)
#pragma unroll
        for (int r = 0; r < 4; ++r)
          pw[(g * 4 + r) * 40 + t * 16 + n] = (_Float16)sc[t][r];

      f16x8 pa = *(f16x8*)(pw + n * 40 + g * 8);   // compiler inserts lgkmcnt wait

      // ---- PV: 4 dh n-tiles ----
#pragma unroll
      for (int nt = 0; nt < 4; ++nt) {
        f16x8 bv = *(f16x8*)(&lds_v[(nt * 16 + n) * 40 + g * 8]);
        o_acc[nt] = __builtin_amdgcn_mfma_f32_16x16x32_f16(pa, bv, o_acc[nt], 0, 0, 0);
      }
    }
    __syncthreads();
  }

  // ---- epilogue: O = acc / l ----
#pragma unroll
  for (int r = 0; r < 4; ++r) {
    int row = qrow_base + g * 4 + r;
    float inv = 1.0f / l_r[r];
    float* op = out + ((size_t)b * S_ + row) * D_ + h * DH + n;
#pragma unroll
    for (int nt = 0; nt < 4; ++nt)
      op[nt * 16] = o_acc[nt][r] * inv;
  }
}

extern "C" void kernel_launch(void* const* d_in, const int* in_sizes, int n_in,
                              void* d_out, int out_size, void* d_ws, size_t ws_size,
                              hipStream_t stream) {
  const float* q = (const float*)d_in[0];
  const float* k = (const float*)d_in[1];
  const float* v = (const float*)d_in[2];
  // d_in[3] is the causal mask (tril by construction) — handled analytically.
  float* out = (float*)d_out;
  dim3 grid(B_ * H_ * NQB);   // 1024
  mha_fwd<<<grid, 256, 0, stream>>>(q, k, v, out);
}

// Round 2
// 206.089 us; speedup vs baseline: 1.2949x; 1.2949x over previous
//
#include <hip/hip_runtime.h>

#define B_ 2
#define S_ 2048
#define D_ 1024
#define H_ 16
#define DH 64
#define QB 64
#define KB 64
#define NQB (S_/QB)     // 32
#define SCALE 0.125f    // 1/sqrt(64)

typedef _Float16 f16x8 __attribute__((ext_vector_type(8)));
typedef float f32x4 __attribute__((ext_vector_type(4)));

// mfma_f32_16x16x32_f16 fragment layouts (gfx950, verified r1):
//   A[m][k]: m = lane&15, k = (lane>>4)*8 + j
//   B[k][n]: n = lane&15, k = (lane>>4)*8 + j
//   D[row][col]: col = lane&15, row = (lane>>4)*4 + reg

__global__ __launch_bounds__(256) void mha_fwd(
    const float* __restrict__ qg, const float* __restrict__ kg,
    const float* __restrict__ vg, float* __restrict__ out)
{
  // K tile: [64 keys][64 dh] halfs, rows 128B, chunk-XOR swizzle (row&7)
  __shared__ __align__(16) _Float16 lds_k[KB * DH];
  // V^T tile: [64 dh][72] halfs (144B rows: 16B-aligned b128 reads)
  __shared__ __align__(16) _Float16 lds_v[DH * 72];
  // P buffer: per-wave [16 rows][72]
  __shared__ __align__(16) _Float16 lds_p[4 * 16 * 72];

  // XCD-aware swizzle: 1024 blocks, 8 XCDs, bh-major chunks (qb-balanced)
  int bx = blockIdx.x;
  int L  = (bx & 7) * 128 + (bx >> 3);
  int qb = L & 31;
  int bh = L >> 5;
  int h  = bh & 15;
  int b  = bh >> 4;

  int tid  = threadIdx.x;
  int wid  = tid >> 6;
  int lane = tid & 63;
  int n    = lane & 15;
  int g    = lane >> 4;

  int qrow_base = qb * QB + wid * 16;

  const float* qbase = qg + (size_t)b * S_ * D_ + h * DH;
  const float* kbase = kg + (size_t)b * S_ * D_ + h * DH;
  const float* vbase = vg + (size_t)b * S_ * D_ + h * DH;

  // ---- Q fragments (registers, whole block lifetime) ----
  f16x8 aq[2];
  {
    const float* qp = qbase + (size_t)(qrow_base + n) * D_ + g * 8;
#pragma unroll
    for (int c = 0; c < 2; ++c) {
      float4 x0 = *(const float4*)(qp + c * 32);
      float4 x1 = *(const float4*)(qp + c * 32 + 4);
      f16x8 a;
      a[0] = (_Float16)(x0.x * SCALE); a[1] = (_Float16)(x0.y * SCALE);
      a[2] = (_Float16)(x0.z * SCALE); a[3] = (_Float16)(x0.w * SCALE);
      a[4] = (_Float16)(x1.x * SCALE); a[5] = (_Float16)(x1.y * SCALE);
      a[6] = (_Float16)(x1.z * SCALE); a[7] = (_Float16)(x1.w * SCALE);
      aq[c] = a;
    }
  }

  f32x4 o_acc[4] = {};
  float m_r[4], l_r[4];
#pragma unroll
  for (int r = 0; r < 4; ++r) { m_r[r] = -1e30f; l_r[r] = 0.f; }

  // staging registers (prefetch) — one K tile + one V tile, 16 floats each
  const int skey  = tid >> 2;
  const int spart = tid & 3;
  float4 kf[4], vf[4];

  auto load_tile = [&](int kt) {
    const float* kp = kbase + (size_t)(kt * KB + skey) * D_ + spart * 16;
    const float* vp = vbase + (size_t)(kt * KB + skey) * D_ + spart * 16;
#pragma unroll
    for (int i = 0; i < 4; ++i) kf[i] = ((const float4*)kp)[i];
#pragma unroll
    for (int i = 0; i < 4; ++i) vf[i] = ((const float4*)vp)[i];
  };

  auto store_tile = [&]() {
    // K: two swizzled f16x8 chunks
    f16x8 h0, h1;
    h0[0]=(_Float16)kf[0].x; h0[1]=(_Float16)kf[0].y; h0[2]=(_Float16)kf[0].z; h0[3]=(_Float16)kf[0].w;
    h0[4]=(_Float16)kf[1].x; h0[5]=(_Float16)kf[1].y; h0[6]=(_Float16)kf[1].z; h0[7]=(_Float16)kf[1].w;
    h1[0]=(_Float16)kf[2].x; h1[1]=(_Float16)kf[2].y; h1[2]=(_Float16)kf[2].z; h1[3]=(_Float16)kf[2].w;
    h1[4]=(_Float16)kf[3].x; h1[5]=(_Float16)kf[3].y; h1[6]=(_Float16)kf[3].z; h1[7]=(_Float16)kf[3].w;
    int c0 = spart * 2;
    *(f16x8*)((char*)lds_k + skey * 128 + (((c0    ) ^ (skey & 7)) << 4)) = h0;
    *(f16x8*)((char*)lds_k + skey * 128 + (((c0 + 1) ^ (skey & 7)) << 4)) = h1;
    // V^T scatter (b16 writes)
    const float* vfl = (const float*)vf;
#pragma unroll
    for (int j = 0; j < 16; ++j)
      lds_v[(spart * 16 + j) * 72 + skey] = (_Float16)vfl[j];
  };

  const int nkt = qb + 1;   // causal: keys 0 .. qb*64+63

  load_tile(0);
  store_tile();
  if (nkt > 1) load_tile(1);
  __syncthreads();

  for (int kt = 0; kt < nkt; ++kt) {
    const int kb = kt * KB;
    if (kb <= qrow_base + 15) {
      // ---- QK^T: 4 key n-tiles x 2 k-chunks ----
      f32x4 sc[4] = {};
#pragma unroll
      for (int t = 0; t < 4; ++t) {
        int keyl = t * 16 + n;
#pragma unroll
        for (int c = 0; c < 2; ++c) {
          int off = keyl * 128 + (((c * 4 + g) ^ (keyl & 7)) << 4);
          f16x8 bk = *(f16x8*)((char*)lds_k + off);
          sc[t] = __builtin_amdgcn_mfma_f32_16x16x32_f16(aq[c], bk, sc[t], 0, 0, 0);
        }
      }
      // ---- causal mask (diagonal region only) ----
      if (kb + KB - 1 > qrow_base) {
#pragma unroll
        for (int t = 0; t < 4; ++t)
#pragma unroll
          for (int r = 0; r < 4; ++r) {
            int key = kb + t * 16 + n;
            int row = qrow_base + g * 4 + r;
            if (key > row) sc[t][r] = -1e30f;
          }
      }
      // ---- online softmax ----
      float alpha[4];
#pragma unroll
      for (int r = 0; r < 4; ++r) {
        float mx = fmaxf(fmaxf(sc[0][r], sc[1][r]), fmaxf(sc[2][r], sc[3][r]));
#pragma unroll
        for (int w = 1; w < 16; w <<= 1) mx = fmaxf(mx, __shfl_xor(mx, w, 64));
        float mnew = fmaxf(m_r[r], mx);
        float a = __expf(m_r[r] - mnew);
        float s = 0.f;
#pragma unroll
        for (int t = 0; t < 4; ++t) {
          float p = __expf(sc[t][r] - mnew);
          sc[t][r] = p; s += p;
        }
#pragma unroll
        for (int w = 1; w < 16; w <<= 1) s += __shfl_xor(s, w, 64);
        l_r[r] = l_r[r] * a + s;
        m_r[r] = mnew;
        alpha[r] = a;
      }
#pragma unroll
      for (int nt = 0; nt < 4; ++nt)
#pragma unroll
        for (int r = 0; r < 4; ++r) o_acc[nt][r] *= alpha[r];

      // ---- P -> LDS (per-wave), then A-fragments ----
      _Float16* pw = lds_p + wid * 16 * 72;
#pragma unroll
      for (int t = 0; t < 4; ++t)
#pragma unroll
        for (int r = 0; r < 4; ++r)
          pw[(g * 4 + r) * 72 + t * 16 + n] = (_Float16)sc[t][r];

      f16x8 pa0 = *(f16x8*)(pw + n * 72 + g * 8);
      f16x8 pa1 = *(f16x8*)(pw + n * 72 + 32 + g * 8);

      // ---- PV: 4 dh n-tiles x 2 key-chunks ----
#pragma unroll
      for (int nt = 0; nt < 4; ++nt) {
        f16x8 bv0 = *(f16x8*)(&lds_v[(nt * 16 + n) * 72 + g * 8]);
        o_acc[nt] = __builtin_amdgcn_mfma_f32_16x16x32_f16(pa0, bv0, o_acc[nt], 0, 0, 0);
        f16x8 bv1 = *(f16x8*)(&lds_v[(nt * 16 + n) * 72 + 32 + g * 8]);
        o_acc[nt] = __builtin_amdgcn_mfma_f32_16x16x32_f16(pa1, bv1, o_acc[nt], 0, 0, 0);
      }
    }
    __syncthreads();
    if (kt + 1 < nkt) {
      store_tile();                       // tile kt+1 regs -> LDS
      if (kt + 2 < nkt) load_tile(kt + 2);  // prefetch ahead
      __syncthreads();
    }
  }

  // ---- epilogue ----
#pragma unroll
  for (int r = 0; r < 4; ++r) {
    int row = qrow_base + g * 4 + r;
    float inv = 1.0f / l_r[r];
    float* op = out + ((size_t)b * S_ + row) * D_ + h * DH + n;
#pragma unroll
    for (int nt = 0; nt < 4; ++nt)
      op[nt * 16] = o_acc[nt][r] * inv;
  }
}

extern "C" void kernel_launch(void* const* d_in, const int* in_sizes, int n_in,
                              void* d_out, int out_size, void* d_ws, size_t ws_size,
                              hipStream_t stream) {
  const float* q = (const float*)d_in[0];
  const float* k = (const float*)d_in[1];
  const float* v = (const float*)d_in[2];
  float* out = (float*)d_out;
  dim3 grid(B_ * H_ * NQB);   // 1024
  mha_fwd<<<grid, 256, 0, stream>>>(q, k, v, out);
}

// Round 4
// 150.608 us; speedup vs baseline: 1.7719x; 1.3684x over previous
//
#include <hip/hip_runtime.h>

#define B_ 2
#define S_ 2048
#define D_ 1024
#define H_ 16
#define DH 64
#define KB 64
#define SCALE 0.125f    // 1/sqrt(64)

typedef _Float16 f16x8 __attribute__((ext_vector_type(8)));
typedef _Float16 f16x4 __attribute__((ext_vector_type(4)));
typedef float f32x4 __attribute__((ext_vector_type(4)));

// Swapped-QK layout (all verified against r1/r2-proven mappings):
//  QK: D = mfma_16x16x32(A=K_frag, B=Q_frag):
//    A[m=key_local][k=dh]: m=lane&15, k=(lane>>4)*8+j  (row-major K, b128 from LDS)
//    B[k=dh][n=q_local]:   n=lane&15, k=(lane>>4)*8+j  (Q from global, per-lane rows)
//    D[row=key_local][col=q_local]: col=lane&15(=q), row=4*(lane>>4)+r(=key)
//    -> lane (n,g) holds P^T[key=16t+4g+r][q=qrow+n]: whole row q=n is lane-local per t,r.
//  PV: D = mfma_16x16x16(A=P, B=V):
//    A[m=q][k=key_local]: m=lane&15(=n, matches!), k=4g+j == lane's own sc[u][r] -> NO shuffle.
//    B[k=key_local][n=dh]: lane needs V[16u+4g+j][nt*16+n], j=0..3 -> b64 from swizzled V^T LDS.
//    D[row=q_local=4g+r][col=dh_local=n].

__global__ __launch_bounds__(256, 2) void mha_fwd(
    const float* __restrict__ qg, const float* __restrict__ kg,
    const float* __restrict__ vg, float* __restrict__ out)
{
  // K tile [64 keys][64 dh] f16, rows 128B, 16B-chunk XOR swizzle (r2-proven pair)
  __shared__ __align__(16) _Float16 lds_k[KB * DH];
  // V^T tile: element (dh,key) at halfs dh*64 + ((key>>3 ^ (dh&7))<<3) + (key&7)
  // write: b128 (8 consec keys), read: b64 (4 consec keys) — both at bank floor
  __shared__ __align__(16) _Float16 lds_v[DH * KB];

  // 512 blocks: XCD-bijective swizzle; bh-major chunks for L2 locality
  int bx = blockIdx.x;
  int L  = (bx & 7) * 64 + (bx >> 3);
  int bh  = L >> 4;     // 0..31
  int qbp = L & 15;     // pair index
  int h = bh & 15;
  int b = bh >> 4;

  int tid  = threadIdx.x;
  int wid  = tid >> 6;
  int lane = tid & 63;
  int n    = lane & 15;
  int g    = lane >> 4;

  const float* qbase = qg + (size_t)b * S_ * D_ + h * DH;
  const float* kbase = kg + (size_t)b * S_ * D_ + h * DH;
  const float* vbase = vg + (size_t)b * S_ * D_ + h * DH;

  // staging roles
  const int skey  = tid >> 2;   // K: one key row per thread
  const int spart = tid & 3;    // K: dh 16-chunk
  const int vdh   = tid & 63;   // V: one dh column per thread
  const int vkq   = tid >> 6;   // V: key quarter (16 keys)

  float4 kf[4];
  float  vf[16];

  for (int ph = 0; ph < 2; ++ph) {
    const int qb   = ph ? (31 - qbp) : qbp;   // paired: 33 tiles total/block
    const int nkt  = qb + 1;
    const int qrow = qb * 64 + wid * 16;      // wave's 16 q-rows

    // ---- Q B-fragments (global, scale folded) ----
    f16x8 bq[2];
    {
      const float* qp = qbase + (size_t)(qrow + n) * D_ + g * 8;
#pragma unroll
      for (int c = 0; c < 2; ++c) {
        float4 x0 = *(const float4*)(qp + c * 32);
        float4 x1 = *(const float4*)(qp + c * 32 + 4);
        f16x8 a;
        a[0]=(_Float16)(x0.x*SCALE); a[1]=(_Float16)(x0.y*SCALE);
        a[2]=(_Float16)(x0.z*SCALE); a[3]=(_Float16)(x0.w*SCALE);
        a[4]=(_Float16)(x1.x*SCALE); a[5]=(_Float16)(x1.y*SCALE);
        a[6]=(_Float16)(x1.z*SCALE); a[7]=(_Float16)(x1.w*SCALE);
        bq[c] = a;
      }
    }

    f32x4 o_acc[4] = {};
    float m_run = -1e30f, l_run = 0.f;

    // ---- prefetch tile 0 ----
    {
      const float* kp = kbase + (size_t)skey * D_ + spart * 16;
#pragma unroll
      for (int i = 0; i < 4; ++i) kf[i] = ((const float4*)kp)[i];
      const float* vp = vbase + (size_t)(vkq * 16) * D_ + vdh;
#pragma unroll
      for (int j = 0; j < 16; ++j) vf[j] = vp[(size_t)j * D_];
    }

    for (int kt = 0; kt < nkt; ++kt) {
      __syncthreads();            // previous compute done; LDS free
      // ---- store K tile (swizzled b128) ----
      {
        const float* kfl = (const float*)kf;
        f16x8 h0, h1;
#pragma unroll
        for (int j = 0; j < 8; ++j) { h0[j] = (_Float16)kfl[j]; h1[j] = (_Float16)kfl[8+j]; }
        int c0 = spart * 2;
        *(f16x8*)((char*)lds_k + skey*128 + (((c0  ) ^ (skey&7))<<4)) = h0;
        *(f16x8*)((char*)lds_k + skey*128 + (((c0+1) ^ (skey&7))<<4)) = h1;
      }
      // ---- store V^T tile (key-contiguous b128, XOR on key-block) ----
      {
        f16x8 h0, h1;
#pragma unroll
        for (int j = 0; j < 8; ++j) { h0[j] = (_Float16)vf[j]; h1[j] = (_Float16)vf[8+j]; }
        int kb8 = vkq * 2;
        _Float16* vt = lds_v + vdh * 64;
        *(f16x8*)(vt + (((kb8  ) ^ (vdh&7)) << 3)) = h0;
        *(f16x8*)(vt + (((kb8+1) ^ (vdh&7)) << 3)) = h1;
      }
      __syncthreads();
      // ---- prefetch next tile (lands during compute) ----
      if (kt + 1 < nkt) {
        const float* kp = kbase + (size_t)((kt+1)*KB + skey) * D_ + spart * 16;
#pragma unroll
        for (int i = 0; i < 4; ++i) kf[i] = ((const float4*)kp)[i];
        const float* vp = vbase + (size_t)((kt+1)*KB + vkq*16) * D_ + vdh;
#pragma unroll
        for (int j = 0; j < 16; ++j) vf[j] = vp[(size_t)j * D_];
      }

      // ---- QK^T (swapped): sc[t][r] = S^T[key=kt*64+16t+4g+r][q=qrow+n] ----
      f32x4 sc[4] = {};
#pragma unroll
      for (int t = 0; t < 4; ++t) {
        int keyl = t * 16 + n;
#pragma unroll
        for (int c = 0; c < 2; ++c) {
          int off = keyl * 128 + (((c*4+g) ^ (keyl&7)) << 4);
          f16x8 ak = *(f16x8*)((char*)lds_k + off);
          sc[t] = __builtin_amdgcn_mfma_f32_16x16x32_f16(ak, bq[c], sc[t], 0, 0, 0);
        }
      }

      // ---- causal mask: wave-uniform, last tile only ----
      if (kt == nkt - 1) {
        int q = qrow + n;
#pragma unroll
        for (int t = 0; t < 4; ++t)
#pragma unroll
          for (int r = 0; r < 4; ++r) {
            int key = kt*KB + t*16 + 4*g + r;
            if (key > q) sc[t][r] = -1e30f;
          }
      }

      // ---- online softmax: lane owns one q-row; 2 shfls total ----
      float mx = sc[0][0];
#pragma unroll
      for (int t = 0; t < 4; ++t)
#pragma unroll
        for (int r = 0; r < 4; ++r) mx = fmaxf(mx, sc[t][r]);
      mx = fmaxf(mx, __shfl_xor(mx, 16, 64));
      mx = fmaxf(mx, __shfl_xor(mx, 32, 64));
      float mnew  = fmaxf(m_run, mx);
      float alpha = __expf(m_run - mnew);
      m_run = mnew;
      float s = 0.f;
#pragma unroll
      for (int t = 0; t < 4; ++t)
#pragma unroll
        for (int r = 0; r < 4; ++r) {
          float p = __expf(sc[t][r] - mnew);
          sc[t][r] = p; s += p;
        }
      l_run = l_run * alpha + s;   // per-lane partial; cross-lane sum deferred to epilogue

      // alpha for o_acc rows q_local = 4g+r (held by lane 4g+r)
      float ar[4];
#pragma unroll
      for (int r = 0; r < 4; ++r) ar[r] = __shfl(alpha, 4*g + r, 64);
#pragma unroll
      for (int nt = 0; nt < 4; ++nt) {
        f32x4 oa = o_acc[nt];
#pragma unroll
        for (int r = 0; r < 4; ++r) oa[r] *= ar[r];
        o_acc[nt] = oa;
      }

      // ---- P A-fragments: lane's own values, no shuffle ----
      f16x4 pa[4];
#pragma unroll
      for (int u = 0; u < 4; ++u) {
        f16x4 p4;
#pragma unroll
        for (int r = 0; r < 4; ++r) p4[r] = (_Float16)sc[u][r];
        pa[u] = p4;
      }

      // ---- PV: 4 key-chunks x 4 dh-tiles of mfma_16x16x16 ----
#pragma unroll
      for (int u = 0; u < 4; ++u) {
#pragma unroll
        for (int nt = 0; nt < 4; ++nt) {
          int dh  = nt*16 + n;
          int off = dh*64 + (((2*u + (g>>1)) ^ (n & 7)) << 3) + ((g & 1) << 2);
          f16x4 bv = *(f16x4*)(lds_v + off);
          o_acc[nt] = __builtin_amdgcn_mfma_f32_16x16x16f16(pa[u], bv, o_acc[nt], 0, 0, 0);
        }
      }
    } // kt

    // ---- epilogue: finish row sums, normalize, store ----
    float lsum = l_run;
    lsum += __shfl_xor(lsum, 16, 64);
    lsum += __shfl_xor(lsum, 32, 64);
    float linv[4];
#pragma unroll
    for (int r = 0; r < 4; ++r) linv[r] = 1.0f / __shfl(lsum, 4*g + r, 64);

    float* ob = out + ((size_t)b * S_ + qrow) * D_ + h * DH;
#pragma unroll
    for (int r = 0; r < 4; ++r) {
      float* op = ob + (size_t)(4*g + r) * D_ + n;
#pragma unroll
      for (int nt = 0; nt < 4; ++nt)
        op[nt*16] = o_acc[nt][r] * linv[r];
    }
  } // ph
}

extern "C" void kernel_launch(void* const* d_in, const int* in_sizes, int n_in,
                              void* d_out, int out_size, void* d_ws, size_t ws_size,
                              hipStream_t stream) {
  const float* q = (const float*)d_in[0];
  const float* k = (const float*)d_in[1];
  const float* v = (const float*)d_in[2];
  // d_in[3]: causal mask (tril by construction) — handled analytically.
  float* out = (float*)d_out;
  dim3 grid(512);   // 32 (b,h) x 16 balanced qb-pairs
  mha_fwd<<<grid, 256, 0, stream>>>(q, k, v, out);
}